// Round 7
// baseline (96.897 us; speedup 1.0000x reference)
//
#include <hip/hip_runtime.h>

typedef long long i64;
typedef unsigned long long u64;

// ---------------------------------------------------------------------------
// Established facts (R1-R16):
//  - int64 inputs; int32 output [total*3] neg then [total] keep.
//  - Harness dur_us = fixed ~43 us fill (256 MiB d_ws poison, untouchable)
//    + kernel (~52-53 us, stable across 6 structurally different variants).
//  - NEUTRAL: R8 (broadcast), R12 (vector scan,128thr), R13 (NT hints),
//    R15 (line probe), R16 (4-wide probe + 16-entry block => serial epochs
//    ~3, near info-theoretic floor). Loads/item +-70%, VALU/item +-50%,
//    epochs 5->3: NO effect on time. Epoch-latency model FALSIFIED.
//  - R10 (K=4 lockstep, waves halved): time x1.66. The ONLY knob that ever
//    moved time is resident wave count.
//  - Nothing saturated: HBM 22%, VALUBusy 45%, occ 71% (VGPR=48 allows 100%).
//  - Surviving hypothesis: PER-WAVE FIXED OVERHEAD (wave churn). 65536 short
//    waves / ~5900 slots = ~11 launch/retire generations; ramp+tail = the
//    29% occupancy gap.
//  - Proven shell: ONE dispatch, width probe, 256-thr blocks, no d_ws, no
//    atomics, no cross-lane intrinsics.
// R17: PERSISTENT GRID-STRIDE. 2048 blocks x 256 thr = 8192 waves (resident
//  capacity), 8 items/thread SEQUENTIAL (not lockstep -- VGPR stays low,
//  occupancy untouched). Ramp once, drain once. Plus one-ahead rand_vals
//  prefetch: next pass's rand load issued before current search, overlapping
//  the rand-load epoch with probe latency.
//  Search body: proven R12 form (interp + 4x ulonglong2 aligned window scan).
// ---------------------------------------------------------------------------

template <typename T>
__device__ __forceinline__ bool interp_member(const T* __restrict__ table,
                                              int L, u64 key) {
    u64 v0 = (u64)table[0];
    u64 vN = (u64)table[L - 1];
    if (key <= v0) return key == v0;
    if (key >= vN) return key == vN;
    // invariant: table[lo] < key < table[hi]
    int lo = 0, hi = L - 1;
    u64 vlo = v0, vhi = vN;
    for (int it = 0; it < 12 && hi - lo > 8; ++it) {
        // f32 is plenty: rounding error ~ window * 6e-8 < 1 entry.
        float f = (float)(key - vlo) * __builtin_amdgcn_rcpf((float)(vhi - vlo));
        int mid = lo + (int)(f * (float)(hi - lo));
        if (mid <= lo) mid = lo + 1;           // clamp => strict shrink both ways
        if (mid >= hi) mid = hi - 1;
        u64 v = (u64)table[mid];
        if (v == key) return true;
        if (v < key) { lo = mid; vlo = v; }
        else         { hi = mid; vhi = v; }
    }
    while (hi - lo > 8) {                      // fallback; w.h.p. never runs
        int mid = lo + ((hi - lo) >> 1);
        u64 v = (u64)table[mid];
        if (v == key) return true;
        if (v < key) lo = mid; else hi = mid;
    }
    // Final scan of interior (lo, hi), <=7 entries.
    // i64 path: 4x 16B loads from aligned base m0 (R12-proven):
    //  - m0 = (lo+1)&~1 in {lo, lo+1}; m0+7 >= hi-1 => window covered.
    //  - clamp m0<=L-8 only fires when lo >= L-8; [L-8, L-1] still covers.
    //  - no false positives: strictly sorted-unique table and
    //    table[lo] < key < table[hi] => entries outside (lo,hi) != key.
    if constexpr (sizeof(T) == 8) {
        if (L >= 8) {
            int m0 = (lo + 1) & ~1;
            if (m0 > L - 8) m0 = L - 8;
            const ulonglong2* p = (const ulonglong2*)(table + m0);
            ulonglong2 a = p[0];
            ulonglong2 b = p[1];
            ulonglong2 c = p[2];
            ulonglong2 d = p[3];
            return (a.x == key) | (a.y == key) | (b.x == key) | (b.y == key) |
                   (c.x == key) | (c.y == key) | (d.x == key) | (d.y == key);
        }
    }
    bool eq = false;                           // int path / tiny-L: scalar scan
    for (int j = lo + 1; j < hi; ++j) eq |= ((u64)table[j] == key);
    return eq;
}

// One item, rand value already in register (prefetched by the caller).
template <typename T>
__device__ __forceinline__ void item_body(
    const T* __restrict__ pos, const T* __restrict__ table,
    int* __restrict__ out_neg, int* __restrict__ out_keep,
    unsigned i, i64 rv, int split, int L, unsigned num_negs)
{
    unsigned b = i / num_negs;   // num_negs=64 -> compiler emits shift
    i64 h = (i64)pos[3 * (size_t)b + 0];
    i64 r = (i64)pos[3 * (size_t)b + 1];
    i64 t = (i64)pos[3 * (size_t)b + 2];

    const bool corrupt_head = (i < (unsigned)split);
    i64 orig = corrupt_head ? h : t;
    // pad_idx==0 fast path: rng drawn in [1, NUM_ENTITIES); shift past original
    i64 repl = rv + (((rv >= orig) & (orig > 0)) ? 1 : 0);
    if (corrupt_head) h = repl; else t = repl;

    u64 key = ((u64)h << 42) | ((u64)r << 21) | (u64)t;

    // Store neg early: fire-and-forget, frees values during the search.
    out_neg[3 * (size_t)i + 0] = (int)h;
    out_neg[3 * (size_t)i + 1] = (int)r;
    out_neg[3 * (size_t)i + 2] = (int)t;

    bool in_set = interp_member(table, L, key);
    out_keep[i] = in_set ? 0 : 1;
}

template <typename T>
__device__ __forceinline__ void persistent_body(
    const T* __restrict__ pos, const T* __restrict__ rand_vals,
    const T* __restrict__ table,
    int* __restrict__ out_neg, int* __restrict__ out_keep,
    unsigned total, unsigned stride, int split, int L, unsigned num_negs)
{
    unsigned i = blockIdx.x * blockDim.x + threadIdx.x;
    if (i >= total) return;

    // one-ahead prefetch of rand_vals: next pass's load is in flight during
    // the current pass's search (its vmcnt retires with the probe waits).
    i64 rv = (i64)rand_vals[i];
    for (; i < total; ) {
        unsigned inext = i + stride;
        i64 rv_next = 0;
        if (inext < total) rv_next = (i64)rand_vals[inext];   // issue EARLY
        item_body<T>(pos, table, out_neg, out_keep, i, rv, split, L, num_negs);
        i = inext;
        rv = rv_next;
    }
}

__global__ __launch_bounds__(256) void neg_sample_kernel(
    const void* __restrict__ pos, const void* __restrict__ rand_vals,
    const void* __restrict__ table,
    int* __restrict__ out_neg, int* __restrict__ out_keep,
    int total, int stride, int split, int L, unsigned num_negs)
{
    // Width probe (R2-proven): pos int32-view word 3 == 0 iff int64 storage.
    const int* pw = (const int*)pos;
    const bool is64 = (pw[3] == 0);   // wave-uniform, L1-hot

    if (is64) {
        persistent_body<i64>((const i64*)pos, (const i64*)rand_vals,
                             (const i64*)table, out_neg, out_keep,
                             (unsigned)total, (unsigned)stride, split, L, num_negs);
    } else {
        persistent_body<int>((const int*)pos, (const int*)rand_vals,
                             (const int*)table, out_neg, out_keep,
                             (unsigned)total, (unsigned)stride, split, L, num_negs);
    }
}

extern "C" void kernel_launch(void* const* d_in, const int* in_sizes, int n_in,
                              void* d_out, int out_size, void* d_ws, size_t ws_size,
                              hipStream_t stream) {
    const void* pos       = d_in[0];
    const void* rand_vals = d_in[1];
    const void* table     = d_in[2];

    const int B     = in_sizes[0] / 3;
    const int total = in_sizes[1];
    const int L     = in_sizes[2];
    const unsigned num_negs = (unsigned)(total / B);
    const int split = (total + 1) / 2;   // ceil(total/2)

    int* out_neg  = (int*)d_out;
    int* out_keep = out_neg + (size_t)total * 3;

    const int threads = 256;
    // Persistent grid: resident capacity (256 CU x 8 WG/CU), grid-stride the
    // rest. For total=4.19M this is 2048 blocks, exactly 8 passes/thread.
    int blocks = (total + threads - 1) / threads;
    const int max_blocks = 2048;
    if (blocks > max_blocks) blocks = max_blocks;
    const int stride = blocks * threads;

    neg_sample_kernel<<<blocks, threads, 0, stream>>>(
        pos, rand_vals, table, out_neg, out_keep, total, stride, split, L,
        num_negs);
}